// Round 5
// baseline (134.532 us; speedup 1.0000x reference)
//
#include <hip/hip_runtime.h>
#include <hip/hip_bf16.h>

typedef __attribute__((ext_vector_type(8))) short short8;
typedef __attribute__((ext_vector_type(4))) short short4v;
typedef __attribute__((ext_vector_type(4))) float f32x4;

static constexpr int BATCH = 2, S = 2048, D = 1024, H = 16, DK = 64;
static constexpr int TOK = BATCH * S;     // 4096
static constexpr int NQKV = 3 * D;        // 3072

__device__ inline unsigned short f2bf(float f) {
  unsigned int u = __builtin_bit_cast(unsigned int, f);
  unsigned int r = (u + 0x7fffu + ((u >> 16) & 1u)) >> 16;
  return (unsigned short)r;
}

__device__ inline unsigned cvt_pk_bf16(float lo, float hi) {
  unsigned r;
  asm("v_cvt_pk_bf16_f32 %0, %1, %2" : "=v"(r) : "v"(lo), "v"(hi));
  return r;
}

__device__ inline float fexp2(float x) { return __builtin_amdgcn_exp2f(x); }

__device__ inline void gload_lds16(const void* g, void* l) {
  __builtin_amdgcn_global_load_lds((const __attribute__((address_space(1))) void*)g,
                                   (__attribute__((address_space(3))) void*)l, 16, 0, 0);
}

// ---------------- fp32 -> bf16 elementwise (+ mask additive table) ----------------
__global__ void k_cvt_bf16(const float* __restrict__ in, unsigned short* __restrict__ out,
                           int n4, const int* __restrict__ mask, float* __restrict__ maskadd,
                           int nmask) {
  const int cvtBlocks = n4 >> 8;
  if ((int)blockIdx.x < cvtBlocks) {
    int i = blockIdx.x * 256 + threadIdx.x;
    float4 v = ((const float4*)in)[i];
    short4v o;
    o[0] = (short)f2bf(v.x); o[1] = (short)f2bf(v.y);
    o[2] = (short)f2bf(v.z); o[3] = (short)f2bf(v.w);
    ((short4v*)out)[i] = o;
  } else {
    int j = (blockIdx.x - cvtBlocks) * 256 + threadIdx.x;
    if (j < nmask) maskadd[j] = mask[j] ? 0.f : -1.0e9f;
  }
}

// ---------------- fp32 [R,C] -> bf16 [C,R] ----------------
__global__ void k_transpose_cvt(const float* __restrict__ in, unsigned short* __restrict__ out,
                                int R, int C) {
  __shared__ float tile[32][33];
  const int tx = threadIdx.x, ty = threadIdx.y;
  const int bc = blockIdx.x * 32, br = blockIdx.y * 32;
#pragma unroll
  for (int i = 0; i < 32; i += 8)
    tile[ty + i][tx] = in[(size_t)(br + ty + i) * C + bc + tx];
  __syncthreads();
#pragma unroll
  for (int i = 0; i < 32; i += 8)
    out[(size_t)(bc + ty + i) * R + br + tx] = f2bf(tile[tx][ty + i]);
}

// ---------------- V slice of qkv -> Vt[B*H, DK, S] ----------------
__global__ __launch_bounds__(256) void k_transpose_v(const unsigned short* __restrict__ qkv,
                                                     unsigned short* __restrict__ vt) {
  const int blk = blockIdx.x;
  const int stile = blk & 31, bh = blk >> 5;
  const int b = bh >> 4, h = bh & 15;
  const int s0 = stile * 64;
  __shared__ alignas(16) unsigned short tile[64][72];
  const int tid = threadIdx.x;
  const unsigned short* src = qkv + (size_t)(b * S + s0) * NQKV + 2 * D + h * DK;
#pragma unroll
  for (int it = 0; it < 2; ++it) {
    const int sl = it * 32 + (tid >> 3);
    const int d0 = (tid & 7) * 8;
    *(short8*)&tile[sl][d0] = *(const short8*)(src + (size_t)sl * NQKV + d0);
  }
  __syncthreads();
  const int d = tid >> 2, sg = tid & 3;
  short8 o0, o1;
#pragma unroll
  for (int j = 0; j < 8; ++j) {
    o0[j] = (short)tile[sg * 16 + j][d];
    o1[j] = (short)tile[sg * 16 + 8 + j][d];
  }
  unsigned short* dst = vt + (size_t)(bh * DK + d) * S + s0 + sg * 16;
  *(short8*)dst = o0;
  *(short8*)(dst + 8) = o1;
}

// ---------------- GEMM: A[M,K] bf16 @ Bt[N,K]^T + bias -> C[M,N] ----------------
template <int OUT_BF16>
__global__ __launch_bounds__(256, 2) void k_gemm(const unsigned short* __restrict__ A,
                                                 const unsigned short* __restrict__ Bt,
                                                 const float* __restrict__ bias,
                                                 void* __restrict__ Cout,
                                                 int M, int N, int K) {
  __shared__ alignas(16) unsigned short As[128 * 64];
  __shared__ alignas(16) unsigned short Bs[128 * 64];
  const int tid = threadIdx.x;
  const int wid = tid >> 6, lane = tid & 63;
  const int lr = lane & 15, lg = lane >> 4;
  const int nbx = N >> 7;
  const int bx = blockIdx.x % nbx, by = blockIdx.x / nbx;
  const int m0 = by << 7, n0 = bx << 7;
  const int wm = (wid >> 1) << 6, wn = (wid & 1) << 6;

  f32x4 acc[4][4] = {};

  const int sk = ((lane & 7) ^ (lane >> 3)) << 4;
  const int srow = lane >> 3;

  const int ktc = K >> 6;
  for (int kt = 0; kt < ktc; ++kt) {
    const int k0 = kt << 6;
    __syncthreads();
#pragma unroll
    for (int c = 0; c < 4; ++c) {
      const int chunk = c * 4 + wid;
      const int mrow = chunk * 8 + srow;
      const char* ga = (const char*)(A + (size_t)(m0 + mrow) * K + k0) + sk;
      gload_lds16(ga, (char*)As + chunk * 1024);
      const char* gb = (const char*)(Bt + (size_t)(n0 + mrow) * K + k0) + sk;
      gload_lds16(gb, (char*)Bs + chunk * 1024);
    }
    __syncthreads();
#pragma unroll
    for (int ks = 0; ks < 2; ++ks) {
      const int kb = ks * 64 + lg * 16;
      const int swz = (lr & 7) << 4;
      short8 af[4], bfr[4];
#pragma unroll
      for (int mf = 0; mf < 4; ++mf) {
        const int m = wm + mf * 16 + lr;
        af[mf] = *(const short8*)((const char*)As + m * 128 + (kb ^ swz));
      }
#pragma unroll
      for (int nf = 0; nf < 4; ++nf) {
        const int n = wn + nf * 16 + lr;
        bfr[nf] = *(const short8*)((const char*)Bs + n * 128 + (kb ^ swz));
      }
#pragma unroll
      for (int mf = 0; mf < 4; ++mf)
#pragma unroll
        for (int nf = 0; nf < 4; ++nf)
          acc[mf][nf] = __builtin_amdgcn_mfma_f32_16x16x32_bf16(af[mf], bfr[nf], acc[mf][nf], 0, 0, 0);
    }
  }
#pragma unroll
  for (int nf = 0; nf < 4; ++nf) {
    const int n = n0 + wn + nf * 16 + lr;
    const float bv = bias[n];
#pragma unroll
    for (int mf = 0; mf < 4; ++mf) {
#pragma unroll
      for (int r = 0; r < 4; ++r) {
        const int m = m0 + wm + mf * 16 + lg * 4 + r;
        const float v = acc[mf][nf][r] + bv;
        if (OUT_BF16)
          ((unsigned short*)Cout)[(size_t)m * N + n] = f2bf(v);
        else
          ((float*)Cout)[(size_t)m * N + n] = v;
      }
    }
  }
}

// ---------------- flash attention v5: swapped-operand MFMA ----------------
// grid = B*H*(S/128) = 512 blocks; 4 waves x 32 q rows (2 m-frags).
// QK^T computed as mfma(K,Q) -> S^T (q = lane-local col lr); PV as mfma(Vt,P) -> O^T.
// P round-trip: b64 packed writes + b128 reads. Softmax m/l are per-lane scalars.
__global__ __launch_bounds__(256, 2) void k_attn(const unsigned short* __restrict__ qkv,
                                                 const unsigned short* __restrict__ vt,
                                                 const float* __restrict__ maskadd,
                                                 unsigned short* __restrict__ attn) {
  __shared__ alignas(16) char Ks[3][8192];        // [64 keys][128B], xor-swizzled
  __shared__ alignas(16) char Vs[3][8192];        // [64 d][128B keys], xor-swizzled
  __shared__ alignas(16) unsigned short P[4][32 * 80];  // per-wave [32 q][80]
  __shared__ float msk[S];                        // additive mask

  constexpr int NT = S / 64;  // 32 tiles

  const int blk = blockIdx.x;
  const int work = (blk & 7) * 64 + (blk >> 3);   // XCD-chunked swizzle (512=8*64)
  const int qt = work & 15;
  const int bh = work >> 4;
  const int b = bh >> 4, h = bh & 15;
  const int tid = threadIdx.x;
  const int wid = tid >> 6, lane = tid & 63;
  const int lr = lane & 15, lg = lane >> 4;
  const int q0 = qt * 128 + wid * 32;

  // mask -> LDS (256 threads x 2 x float4)
#pragma unroll
  for (int j = 0; j < 2; ++j)
    *(float4*)&msk[(j * 256 + tid) * 4] = *(const float4*)(maskadd + b * S + (j * 256 + tid) * 4);

  // Q fragments: Q[q = mq*16+lr][d = ks*32 + lg*8 ..+7] (B-operand layout)
  const unsigned short* qbase = qkv + (size_t)(b * S + q0) * NQKV + h * DK;
  short8 qf[2][2];
#pragma unroll
  for (int mq = 0; mq < 2; ++mq)
#pragma unroll
    for (int ks = 0; ks < 2; ++ks)
      qf[mq][ks] = *(const short8*)(qbase + (size_t)(mq * 16 + lr) * NQKV + ks * 32 + lg * 8);

  const unsigned short* kg0 = qkv + ((size_t)b * S * NQKV + D + h * DK);
  const unsigned short* vg0 = vt + (size_t)bh * DK * S;
  const int srow = lane >> 3;
  const int sk = ((lane & 7) ^ srow) << 4;

  auto stage = [&](int buf, int kt) {
    const int kbase = kt * 64;
    const int r1 = wid * 8 + srow, r2 = r1 + 32;
    gload_lds16((const char*)(kg0 + (size_t)(kbase + r1) * NQKV) + sk, Ks[buf] + r1 * 128);
    gload_lds16((const char*)(kg0 + (size_t)(kbase + r2) * NQKV) + sk, Ks[buf] + r2 * 128);
    gload_lds16((const char*)(vg0 + (size_t)r1 * S + kbase) + sk, Vs[buf] + r1 * 128);
    gload_lds16((const char*)(vg0 + (size_t)r2 * S + kbase) + sk, Vs[buf] + r2 * 128);
  };

  f32x4 o[2][4] = {};
  float m2[2] = {-1e30f, -1e30f};
  float lpart[2] = {0.f, 0.f};

  constexpr float C2 = 0.125f * 1.44269504088896f;  // scale * log2(e)
  const int rswz = (lr & 7) << 4;
  char* pw = (char*)&P[wid][0];

  // prologue: 2 stages in flight; drain LDS writes (mask) before first barrier
  stage(0, 0);
  stage(1, 1);
  asm volatile("s_waitcnt lgkmcnt(0)" ::: "memory");

  auto compute = [&](int cur, int kt) {
    const int kbase = kt * 64;

    // mask adds: per lane 4 consecutive keys (kf*16 + lg*4 + r)
    f32x4 add_[4];
#pragma unroll
    for (int kf = 0; kf < 4; ++kf)
      add_[kf] = *(const f32x4*)&msk[kbase + kf * 16 + lg * 4];

    // K fragments (A-operand): K[key = kf*16+lr][d = ks*32 + lg*8]
    short8 kfr[4][2];
#pragma unroll
    for (int kf = 0; kf < 4; ++kf)
#pragma unroll
      for (int ks = 0; ks < 2; ++ks)
        kfr[kf][ks] = *(const short8*)(Ks[cur] + (kf * 16 + lr) * 128 + ((ks * 64 + lg * 16) ^ rswz));

    // swapped QK^T: sc[mq][kf][r] = S[key = kf*16+lg*4+r][q = mq*16+lr]
    f32x4 sc[2][4];
#pragma unroll
    for (int mq = 0; mq < 2; ++mq)
#pragma unroll
      for (int kf = 0; kf < 4; ++kf) {
        f32x4 t = {};
        t = __builtin_amdgcn_mfma_f32_16x16x32_bf16(kfr[kf][0], qf[mq][0], t, 0, 0, 0);
        t = __builtin_amdgcn_mfma_f32_16x16x32_bf16(kfr[kf][1], qf[mq][1], t, 0, 0, 0);
        sc[mq][kf] = t;
      }
#pragma unroll
    for (int mq = 0; mq < 2; ++mq)
#pragma unroll
      for (int kf = 0; kf < 4; ++kf)
#pragma unroll
        for (int r = 0; r < 4; ++r)
          sc[mq][kf][r] = sc[mq][kf][r] * C2 + add_[kf][r];

    // per-lane partial max (q = lr, keys are lane-local) + defer-max vote
    float pmax[2];
#pragma unroll
    for (int mq = 0; mq < 2; ++mq) {
      f32x4 m4 = sc[mq][0];
#pragma unroll
      for (int kf = 1; kf < 4; ++kf)
#pragma unroll
        for (int r = 0; r < 4; ++r) m4[r] = fmaxf(m4[r], sc[mq][kf][r]);
      pmax[mq] = fmaxf(fmaxf(m4[0], m4[1]), fmaxf(m4[2], m4[3]));
    }
    const float worst = fmaxf(pmax[0] - m2[0], pmax[1] - m2[1]);
    if (!__all(worst <= 6.0f)) {
      // rare path: true row max across lg groups, rescale O and partial sums
#pragma unroll
      for (int mq = 0; mq < 2; ++mq) {
        float pm = pmax[mq];
        pm = fmaxf(pm, __shfl_xor(pm, 16));
        pm = fmaxf(pm, __shfl_xor(pm, 32));
        const float mnew = fmaxf(m2[mq], pm);
        const float fac = fexp2(m2[mq] - mnew);
        m2[mq] = mnew;
        lpart[mq] *= fac;
#pragma unroll
        for (int df = 0; df < 4; ++df)
#pragma unroll
          for (int r = 0; r < 4; ++r) o[mq][df][r] *= fac;
      }
    }

    // p = exp2(sc - m); accumulate per-lane partial sums (tree)
#pragma unroll
    for (int mq = 0; mq < 2; ++mq) {
      float ps = 0.f;
#pragma unroll
      for (int kf = 0; kf < 4; ++kf) {
#pragma unroll
        for (int r = 0; r < 4; ++r) {
          const float p = fexp2(sc[mq][kf][r] - m2[mq]);
          sc[mq][kf][r] = p;
        }
        ps += (sc[mq][kf][0] + sc[mq][kf][1]) + (sc[mq][kf][2] + sc[mq][kf][3]);
      }
      lpart[mq] += ps;
    }

    // V fragments (A-operand): Vt[d = df*16+lr][key = ks*32 + lg*8]
    short8 vfr[4][2];
#pragma unroll
    for (int df = 0; df < 4; ++df)
#pragma unroll
      for (int ks = 0; ks < 2; ++ks)
        vfr[df][ks] = *(const short8*)(Vs[cur] + (df * 16 + lr) * 128 + ((ks * 64 + lg * 16) ^ rswz));

    // P -> LDS: packed b64 writes (4 consecutive keys per lane), [q][80] layout
#pragma unroll
    for (int mq = 0; mq < 2; ++mq)
#pragma unroll
      for (int kf = 0; kf < 4; ++kf) {
        uint2 w;
        w.x = cvt_pk_bf16(sc[mq][kf][0], sc[mq][kf][1]);
        w.y = cvt_pk_bf16(sc[mq][kf][2], sc[mq][kf][3]);
        *(uint2*)(pw + (mq * 16 + lr) * 160 + kf * 32 + lg * 8) = w;
      }
    asm volatile("s_waitcnt lgkmcnt(0)" ::: "memory");

    // P B-fragments: P[q = mq*16+lr][keys ks*32 + lg*8 ..+7]
    short8 pb[2][2];
#pragma unroll
    for (int mq = 0; mq < 2; ++mq)
#pragma unroll
      for (int ks = 0; ks < 2; ++ks)
        pb[mq][ks] = *(const short8*)(pw + (mq * 16 + lr) * 160 + ks * 64 + lg * 16);

    // swapped PV: o[mq][df][r] = O[q = mq*16+lr][d = df*16+lg*4+r]
#pragma unroll
    for (int df = 0; df < 4; ++df)
#pragma unroll
      for (int mq = 0; mq < 2; ++mq) {
        o[mq][df] = __builtin_amdgcn_mfma_f32_16x16x32_bf16(vfr[df][0], pb[mq][0], o[mq][df], 0, 0, 0);
        o[mq][df] = __builtin_amdgcn_mfma_f32_16x16x32_bf16(vfr[df][1], pb[mq][1], o[mq][df], 0, 0, 0);
      }
  };

  int cur = 0;
  for (int kt = 0; kt < NT - 1; ++kt) {
    // stage(kt) complete once <=4 vmem ops (stage kt+1) remain; never drain to 0
    asm volatile("s_waitcnt vmcnt(4)" ::: "memory");
    __builtin_amdgcn_s_barrier();
    __builtin_amdgcn_sched_barrier(0);
    if (kt + 2 < NT) {
      int nb = cur + 2; if (nb >= 3) nb -= 3;
      stage(nb, kt + 2);
    }
    compute(cur, kt);
    ++cur; if (cur == 3) cur = 0;
  }
  asm volatile("s_waitcnt vmcnt(0)" ::: "memory");
  __builtin_amdgcn_s_barrier();
  __builtin_amdgcn_sched_barrier(0);
  compute(cur, NT - 1);

  // epilogue: reduce partial sums across lg groups, normalize, packed store
#pragma unroll
  for (int mq = 0; mq < 2; ++mq) {
    float s = lpart[mq];
    s += __shfl_xor(s, 16);
    s += __shfl_xor(s, 32);
    const float inv = 1.0f / s;
    unsigned short* orow = attn + (size_t)(b * S + q0 + mq * 16 + lr) * D + h * DK;
#pragma unroll
    for (int df = 0; df < 4; ++df) {
      uint2 w;
      w.x = cvt_pk_bf16(o[mq][df][0] * inv, o[mq][df][1] * inv);
      w.y = cvt_pk_bf16(o[mq][df][2] * inv, o[mq][df][3] * inv);
      *(uint2*)(orow + df * 16 + lg * 4) = w;
    }
  }
}

extern "C" void kernel_launch(void* const* d_in, const int* in_sizes, int n_in,
                              void* d_out, int out_size, void* d_ws, size_t ws_size,
                              hipStream_t stream) {
  const float* x = (const float*)d_in[0];
  const int* mask = (const int*)d_in[1];
  const float* W_qkv = (const float*)d_in[2];
  const float* b_qkv = (const float*)d_in[3];
  const float* W_out = (const float*)d_in[4];
  const float* b_out = (const float*)d_in[5];
  float* out = (float*)d_out;

  char* ws = (char*)d_ws;
  unsigned short* x_bf   = (unsigned short*)(ws);                          // 8 MB
  unsigned short* wqkv_t = (unsigned short*)(ws + (size_t)(8 << 20));      // 6 MB
  unsigned short* wout_t = (unsigned short*)(ws + (size_t)(14 << 20));     // 2 MB
  unsigned short* qkv    = (unsigned short*)(ws + (size_t)(16 << 20));     // 24 MB
  unsigned short* vtr    = (unsigned short*)(ws + (size_t)(40 << 20));     // 8 MB
  unsigned short* attn   = (unsigned short*)(ws + (size_t)(48 << 20));     // 8 MB
  float*          madd   = (float*)(ws + (size_t)(56 << 20));              // 16 KB

  const int n4 = TOK * D / 4;
  k_cvt_bf16<<<n4 / 256 + (TOK + 255) / 256, 256, 0, stream>>>(x, x_bf, n4, mask, madd, TOK);
  k_transpose_cvt<<<dim3(NQKV / 32, D / 32), dim3(32, 8), 0, stream>>>(W_qkv, wqkv_t, D, NQKV);
  k_transpose_cvt<<<dim3(D / 32, D / 32), dim3(32, 8), 0, stream>>>(W_out, wout_t, D, D);
  k_gemm<1><<<(TOK / 128) * (NQKV / 128), 256, 0, stream>>>(x_bf, wqkv_t, b_qkv, qkv, TOK, NQKV, D);
  k_transpose_v<<<BATCH * H * (S / 64), 256, 0, stream>>>(qkv, vtr);
  k_attn<<<BATCH * H * (S / 128), 256, 0, stream>>>(qkv, vtr, madd, attn);
  k_gemm<0><<<(TOK / 128) * (D / 128), 256, 0, stream>>>(attn, wout_t, b_out, out, TOK, D, D);
}